// Round 7
// baseline (136.155 us; speedup 1.0000x reference)
//
#include <hip/hip_runtime.h>
#include <hip/hip_bf16.h>
#include <stdint.h>

#define T_DIM 8192
#define B_DIM 8
#define D_DIM 512
#define O_DIM 512

typedef __attribute__((ext_vector_type(4))) float f32x4;
typedef __attribute__((ext_vector_type(8))) short short8;
typedef __attribute__((ext_vector_type(4))) unsigned short us4;

__device__ __forceinline__ unsigned short f2bf(float f) {
  union { float f; uint32_t u; } v; v.f = f;
  uint32_t u = v.u + 0x7FFFu + ((v.u >> 16) & 1u);   // RNE
  return (unsigned short)(u >> 16);
}

__device__ __forceinline__ void gload_lds16(const void* g, void* l) {
  __builtin_amdgcn_global_load_lds(
      (const __attribute__((address_space(1))) void*)g,
      (__attribute__((address_space(3))) void*)l, 16, 0, 0);
}

__device__ __forceinline__ float clip_lam(const float* decay) {
  return fminf(fmaxf(decay[0], 0.5f), 0.999f);
}

// ---------------------------------------------------------------------------
// Pass 1: h_avg = mean_b x  AND  xbf = bf16(x).  8-deep batched MLP.
__global__ void mean_cvt_kernel(const float* __restrict__ x, float* __restrict__ havg,
                                unsigned short* __restrict__ xbf) {
  int idx = blockIdx.x * 256 + threadIdx.x;           // over T*D/4
  const f32x4* x4 = (const f32x4*)x;
  us4* xb4 = (us4*)xbf;
  const size_t stride = (size_t)T_DIM * D_DIM / 4;
  f32x4 v[8];
#pragma unroll
  for (int b = 0; b < B_DIM; ++b) v[b] = x4[(size_t)b * stride + idx];   // 8 in flight
  us4 o[8];
#pragma unroll
  for (int b = 0; b < B_DIM; ++b)
#pragma unroll
    for (int j = 0; j < 4; ++j) o[b][j] = f2bf(v[b][j]);
#pragma unroll
  for (int b = 0; b < B_DIM; ++b) xb4[(size_t)b * stride + idx] = o[b];
  f32x4 s = ((v[0] + v[1]) + (v[2] + v[3])) + ((v[4] + v[5]) + (v[6] + v[7]));
  s *= 0.125f;
  ((f32x4*)havg)[idx] = s;
}

// ---------------------------------------------------------------------------
// Pass 2: W (2D x O, f32, [k][n]) -> Wt bf16 n-major: Wt[h][n][k]=W[h*512+k][n]
__global__ void wconv_kernel(const float* __restrict__ W, unsigned short* __restrict__ Wt) {
  __shared__ float tile[64][65];
  int bk = blockIdx.x >> 3;
  int bn = blockIdx.x & 7;
  int tr = threadIdx.x >> 4;
  int tc = threadIdx.x & 15;
#pragma unroll
  for (int i = 0; i < 4; ++i) {
    int row = i * 16 + tr;
    f32x4 v = *(const f32x4*)&W[(size_t)(bk * 64 + row) * O_DIM + bn * 64 + tc * 4];
#pragma unroll
    for (int j = 0; j < 4; ++j) tile[row][tc * 4 + j] = v[j];
  }
  __syncthreads();
#pragma unroll
  for (int i = 0; i < 4; ++i) {
    int nl = i * 16 + tr;
    us4 o;
#pragma unroll
    for (int j = 0; j < 4; ++j) o[j] = f2bf(tile[tc * 4 + j][nl]);
    int kg = bk * 64 + tc * 4;
    int h = kg >> 9;
    int k = kg & 511;
    *(us4*)&Wt[(size_t)h * (512 * 512) + (size_t)(bn * 64 + nl) * 512 + k] = o;
  }
}

// ---------------------------------------------------------------------------
// Exact 3-pass chunked EMA scan. CHUNK=128, NCHUNK=64.
#define CHUNK 128
#define NCHUNK (T_DIM / CHUNK)

__global__ void scanA_kernel(float* __restrict__ havg, const float* __restrict__ decay) {
  int chunk = blockIdx.x >> 1;
  int d = ((blockIdx.x & 1) << 8) + threadIdx.x;
  float lam = clip_lam(decay);
  float om = 1.0f - lam;
  size_t base = (size_t)chunk * CHUNK * D_DIM + d;
  float cur[16], nxt[16];
#pragma unroll
  for (int i = 0; i < 16; ++i) cur[i] = havg[base + (size_t)i * D_DIM];
  float s = 0.f;
  for (int blk = 0; blk < 8; ++blk) {
    if (blk < 7) {
#pragma unroll
      for (int i = 0; i < 16; ++i)
        nxt[i] = havg[base + (size_t)((blk + 1) * 16 + i) * D_DIM];
    }
#pragma unroll
    for (int i = 0; i < 16; ++i) {
      s = lam * s + om * cur[i];
      havg[base + (size_t)(blk * 16 + i) * D_DIM] = s;
    }
#pragma unroll
    for (int i = 0; i < 16; ++i) cur[i] = nxt[i];
  }
}

__global__ void scanB_kernel(const float* __restrict__ havg, const float* __restrict__ decay,
                             float* __restrict__ carry) {
  int d = blockIdx.x * 256 + threadIdx.x;
  float lam = clip_lam(decay);
  float l2 = lam * lam;
  float l4 = l2 * l2;
  float l8 = l4 * l4;
  float l16 = l8 * l8;
  float l32 = l16 * l16;
  float l64 = l32 * l32;
  float l128 = l64 * l64;
  float e[NCHUNK];
#pragma unroll
  for (int c = 0; c < NCHUNK; ++c)
    e[c] = havg[((size_t)c * CHUNK + CHUNK - 1) * D_DIM + d];
  float s = 0.f;
#pragma unroll
  for (int c = 0; c < NCHUNK; ++c) {
    s = l128 * s + e[c];
    carry[c * D_DIM + d] = s;
  }
}

__global__ void scanC_kernel(const float* __restrict__ havg, const float* __restrict__ carry,
                             const float* __restrict__ decay, unsigned short* __restrict__ st) {
  int idx = blockIdx.x * 256 + threadIdx.x;
  int t = idx >> 7;
  int d4 = idx & 127;
  int c = t >> 7;
  int k = t & 127;
  float lam = clip_lam(decay);
  float w = exp2f((float)(k + 1) * __log2f(lam));
  f32x4 p = ((const f32x4*)havg)[idx];
  f32x4 cin = {0.f, 0.f, 0.f, 0.f};
  if (c > 0) cin = ((const f32x4*)carry)[(size_t)(c - 1) * 128 + d4];
  us4 o;
#pragma unroll
  for (int j = 0; j < 4; ++j) o[j] = f2bf(p[j] + w * cin[j]);
  ((us4*)st)[idx] = o;
}

// ---------------------------------------------------------------------------
// bf16 GEMM: C[M][512] = A[M][512] @ Bt^T + epilogue. 128x128, BK=32, 4 waves.
// Double-buffered + COUNTED vmcnt (T4): two raw s_barriers per K-step, next
// tile's 4 loads stay in flight across both.  32KB LDS -> up to 5 blocks/CU:
// concurrency = 1-deep prefetch + 4-5 resident blocks covers ~900cy HBM lat.
// 16B-octet XOR swizzle on both LDS tiles (pre-swizzled global source).
template <bool ADD_SBAR>
__global__ __launch_bounds__(256, 4)
void gemm128bf(const unsigned short* __restrict__ A, const unsigned short* __restrict__ Bt,
               const float* __restrict__ extra, float* __restrict__ C) {
  __shared__ __align__(16) char smem[2][16384];   // [buf][A 8KB | B 8KB]

  int nwg = gridDim.x;
  int bid = blockIdx.x;
  int swz = (bid & 7) * (nwg >> 3) + (bid >> 3);
  int tm = swz >> 2, tn = swz & 3;
  int brow = tm << 7, bcol = tn << 7;

  int tid = threadIdx.x;
  int wave = tid >> 6, lane = tid & 63;
  int wr = (wave >> 1) << 6, wc = (wave & 1) << 6;
  const int lr = lane & 15, lkb = lane >> 4;

  // staging: lane covers (row-local = lane>>2, slot = lane&3);
  // swizzled global octet = (lane&3) ^ ((lane>>3)&3); read inverse = (lr>>1)&3
  const int soct = ((lane & 3) ^ ((lane >> 3) & 3)) << 3;
  const int pm = (lr >> 1) & 3;

  const size_t a_base = (size_t)(brow + (wave << 4) + (lane >> 2)) * 512 + soct;
  const size_t b_base = (size_t)(bcol + (wave << 4) + (lane >> 2)) * 512 + soct;

  f32x4 acc[4][4];
#pragma unroll
  for (int m = 0; m < 4; ++m)
#pragma unroll
    for (int n = 0; n < 4; ++n) acc[m][n] = (f32x4){0.f, 0.f, 0.f, 0.f};

  // chunk q = it*4+wave covers tile rows [q*16,q*16+16): it step = 64 rows = it<<15 elems
#define STAGE(buf, kt_)                                                        \
  {                                                                            \
    int k0_ = (kt_) << 5;                                                      \
    _Pragma("unroll")                                                          \
    for (int it = 0; it < 2; ++it)                                             \
      gload_lds16(A + a_base + (size_t)(it << 15) + k0_,                       \
                  &smem[buf][(((it << 2) + wave) << 10)]);                     \
    _Pragma("unroll")                                                          \
    for (int it = 0; it < 2; ++it)                                             \
      gload_lds16(Bt + b_base + (size_t)(it << 15) + k0_,                      \
                  &smem[buf][8192 + (((it << 2) + wave) << 10)]);              \
  }

  STAGE(0, 0);                                    // 4 loads in flight

#pragma unroll 2
  for (int kt = 0; kt < 16; ++kt) {
    const int cur = kt & 1;
    if (kt < 15) {
      STAGE(cur ^ 1, kt + 1);                     // 8 in flight
      asm volatile("s_waitcnt vmcnt(4)" ::: "memory");   // cur's 4 done
    } else {
      asm volatile("s_waitcnt vmcnt(0)" ::: "memory");
    }
    __builtin_amdgcn_s_barrier();                 // all waves: cur ready
    __builtin_amdgcn_sched_barrier(0);

    const unsigned short* As = (const unsigned short*)&smem[cur][0];
    const unsigned short* Bs = (const unsigned short*)&smem[cur][8192];
    short8 af[4], bfr[4];
#pragma unroll
    for (int m = 0; m < 4; ++m)
      af[m] = *(const short8*)(As + (size_t)(wr + (m << 4) + lr) * 32 + ((lkb ^ pm) << 3));
#pragma unroll
    for (int n = 0; n < 4; ++n)
      bfr[n] = *(const short8*)(Bs + (size_t)(wc + (n << 4) + lr) * 32 + ((lkb ^ pm) << 3));

#pragma unroll
    for (int m = 0; m < 4; ++m)
#pragma unroll
      for (int n = 0; n < 4; ++n)
        acc[m][n] = __builtin_amdgcn_mfma_f32_16x16x32_bf16(af[m], bfr[n], acc[m][n], 0, 0, 0);

    __builtin_amdgcn_sched_barrier(0);
    __builtin_amdgcn_s_barrier();                 // reads of cur done ->
  }                                               // next STAGE may overwrite
#undef STAGE

  // ---- epilogue: per-wave LDS transpose, 16 rows at a time ([16][68] f32) ----
  float* tp = (float*)&smem[0][0] + (size_t)wave * 2048;   // disjoint 8KB/wave
#pragma unroll
  for (int m = 0; m < 4; ++m) {
#pragma unroll
    for (int n = 0; n < 4; ++n)
#pragma unroll
      for (int j = 0; j < 4; ++j)
        tp[((lkb << 2) + j) * 68 + (n << 4) + lr] = acc[m][n][j];
    __syncthreads();
#pragma unroll
    for (int p = 0; p < 4; ++p) {
      int rl = (p << 2) + (lane >> 4);            // 0..15
      int c0 = (lane & 15) << 2;                  // 0..60
      f32x4 v = *(const f32x4*)(tp + rl * 68 + c0);
      int row = brow + wr + (m << 4) + rl;
      int col = bcol + wc + c0;
      f32x4 e;
      if constexpr (ADD_SBAR)
        e = *(const f32x4*)&extra[(size_t)(row & (T_DIM - 1)) * O_DIM + col];
      else
        e = *(const f32x4*)&extra[col];
      v += e;
      *(f32x4*)&C[(size_t)row * O_DIM + col] = v;
    }
    __syncthreads();
  }
}

// ---------------------------------------------------------------------------
extern "C" void kernel_launch(void* const* d_in, const int* in_sizes, int n_in,
                              void* d_out, int out_size, void* d_ws, size_t ws_size,
                              hipStream_t stream) {
  (void)in_sizes; (void)n_in; (void)out_size; (void)ws_size;
  const float* x     = (const float*)d_in[0];   // [8][8192][512]
  const float* W     = (const float*)d_in[1];   // [1024][512]
  const float* bias  = (const float*)d_in[2];   // [512]
  const float* decay = (const float*)d_in[3];   // [1]
  float* out = (float*)d_out;                   // [8][8192][512]

  char* ws = (char*)d_ws;
  size_t off = 0;
  float*          havg  = (float*)(ws + off);          off += 16777216;  // 16 MiB
  unsigned short* st    = (unsigned short*)(ws + off); off += 8388608;   //  8 MiB
  unsigned short* Wt    = (unsigned short*)(ws + off); off += 1048576;   //  1 MiB
  float*          sbar  = (float*)(ws + off);          off += 16777216;  // 16 MiB
  float*          carry = (float*)(ws + off);          off += 131072;    // 128 KiB
  unsigned short* xbf   = (unsigned short*)(ws + off); off += (size_t)B_DIM * T_DIM * D_DIM * 2; // 64 MiB

  mean_cvt_kernel<<<T_DIM * D_DIM / 4 / 256, 256, 0, stream>>>(x, havg, xbf);
  wconv_kernel<<<128, 256, 0, stream>>>(W, Wt);
  scanA_kernel<<<NCHUNK * 2, 256, 0, stream>>>(havg, decay);
  scanB_kernel<<<2, 256, 0, stream>>>(havg, decay, carry);
  scanC_kernel<<<T_DIM * D_DIM / 4 / 256, 256, 0, stream>>>(havg, carry, decay, st);
  // sbar[t][o] = states @ W_s + b   (M=8192)
  gemm128bf<false><<<(T_DIM / 128) * 4, 256, 0, stream>>>(st, Wt + 512 * 512, bias, sbar);
  // out[b*T+t][o] = x @ W_h + sbar[t][o]   (M=65536)
  gemm128bf<true><<<(B_DIM * T_DIM / 128) * 4, 256, 0, stream>>>(xbf, Wt, sbar, out);
}

// Round 8
// 129.781 us; speedup vs baseline: 1.0491x; 1.0491x over previous
//
#include <hip/hip_runtime.h>
#include <hip/hip_bf16.h>
#include <stdint.h>

#define T_DIM 8192
#define B_DIM 8
#define D_DIM 512
#define O_DIM 512

typedef __attribute__((ext_vector_type(4))) float f32x4;
typedef __attribute__((ext_vector_type(8))) short short8;
typedef __attribute__((ext_vector_type(4))) unsigned short us4;
typedef __attribute__((ext_vector_type(4))) uint32_t u32x4;

__device__ __forceinline__ unsigned short f2bf(float f) {
  union { float f; uint32_t u; } v; v.f = f;
  uint32_t u = v.u + 0x7FFFu + ((v.u >> 16) & 1u);   // RNE
  return (unsigned short)(u >> 16);
}

__device__ __forceinline__ uint32_t cvtpk(float a, float b) {
  uint32_t r;
  asm("v_cvt_pk_bf16_f32 %0, %1, %2" : "=v"(r) : "v"(a), "v"(b));
  return r;
}

__device__ __forceinline__ void gload_lds16(const void* g, void* l) {
  __builtin_amdgcn_global_load_lds(
      (const __attribute__((address_space(1))) void*)g,
      (__attribute__((address_space(3))) void*)l, 16, 0, 0);
}

__device__ __forceinline__ float clip_lam(const float* decay) {
  return fminf(fmaxf(decay[0], 0.5f), 0.999f);
}

// ---------------------------------------------------------------------------
// Pass 1: h_avg[t][d] = mean_b x[b][t][d].  Batched loads.
__global__ void mean_kernel(const float* __restrict__ x, float* __restrict__ havg) {
  int idx = blockIdx.x * 256 + threadIdx.x;           // over T*D/4
  const f32x4* x4 = (const f32x4*)x;
  const size_t stride = (size_t)T_DIM * D_DIM / 4;
  f32x4 v[8];
#pragma unroll
  for (int b = 0; b < B_DIM; ++b) v[b] = x4[(size_t)b * stride + idx];
  f32x4 s = ((v[0] + v[1]) + (v[2] + v[3])) + ((v[4] + v[5]) + (v[6] + v[7]));
  s *= 0.125f;
  ((f32x4*)havg)[idx] = s;
}

// ---------------------------------------------------------------------------
// Pass 2: W (2D x O, f32, [k][n]) -> Wt bf16 n-major: Wt[h][n][k]=W[h*512+k][n]
__global__ void wconv_kernel(const float* __restrict__ W, unsigned short* __restrict__ Wt) {
  __shared__ float tile[64][65];
  int bk = blockIdx.x >> 3;
  int bn = blockIdx.x & 7;
  int tr = threadIdx.x >> 4;
  int tc = threadIdx.x & 15;
#pragma unroll
  for (int i = 0; i < 4; ++i) {
    int row = i * 16 + tr;
    f32x4 v = *(const f32x4*)&W[(size_t)(bk * 64 + row) * O_DIM + bn * 64 + tc * 4];
#pragma unroll
    for (int j = 0; j < 4; ++j) tile[row][tc * 4 + j] = v[j];
  }
  __syncthreads();
#pragma unroll
  for (int i = 0; i < 4; ++i) {
    int nl = i * 16 + tr;
    us4 o;
#pragma unroll
    for (int j = 0; j < 4; ++j) o[j] = f2bf(tile[tc * 4 + j][nl]);
    int kg = bk * 64 + tc * 4;
    int h = kg >> 9;
    int k = kg & 511;
    *(us4*)&Wt[(size_t)h * (512 * 512) + (size_t)(bn * 64 + nl) * 512 + k] = o;
  }
}

// ---------------------------------------------------------------------------
// Exact 3-pass chunked EMA scan. CHUNK=128, NCHUNK=64.
#define CHUNK 128
#define NCHUNK (T_DIM / CHUNK)

__global__ void scanA_kernel(float* __restrict__ havg, const float* __restrict__ decay) {
  int chunk = blockIdx.x >> 1;
  int d = ((blockIdx.x & 1) << 8) + threadIdx.x;
  float lam = clip_lam(decay);
  float om = 1.0f - lam;
  size_t base = (size_t)chunk * CHUNK * D_DIM + d;
  float cur[16], nxt[16];
#pragma unroll
  for (int i = 0; i < 16; ++i) cur[i] = havg[base + (size_t)i * D_DIM];
  float s = 0.f;
  for (int blk = 0; blk < 8; ++blk) {
    if (blk < 7) {
#pragma unroll
      for (int i = 0; i < 16; ++i)
        nxt[i] = havg[base + (size_t)((blk + 1) * 16 + i) * D_DIM];
    }
#pragma unroll
    for (int i = 0; i < 16; ++i) {
      s = lam * s + om * cur[i];
      havg[base + (size_t)(blk * 16 + i) * D_DIM] = s;
    }
#pragma unroll
    for (int i = 0; i < 16; ++i) cur[i] = nxt[i];
  }
}

__global__ void scanB_kernel(const float* __restrict__ havg, const float* __restrict__ decay,
                             float* __restrict__ carry) {
  int d = blockIdx.x * 256 + threadIdx.x;
  float lam = clip_lam(decay);
  float l2 = lam * lam;
  float l4 = l2 * l2;
  float l8 = l4 * l4;
  float l16 = l8 * l8;
  float l32 = l16 * l16;
  float l64 = l32 * l32;
  float l128 = l64 * l64;
  float e[NCHUNK];
#pragma unroll
  for (int c = 0; c < NCHUNK; ++c)
    e[c] = havg[((size_t)c * CHUNK + CHUNK - 1) * D_DIM + d];
  float s = 0.f;
#pragma unroll
  for (int c = 0; c < NCHUNK; ++c) {
    s = l128 * s + e[c];
    carry[c * D_DIM + d] = s;
  }
}

__global__ void scanC_kernel(const float* __restrict__ havg, const float* __restrict__ carry,
                             const float* __restrict__ decay, unsigned short* __restrict__ st) {
  int idx = blockIdx.x * 256 + threadIdx.x;
  int t = idx >> 7;
  int d4 = idx & 127;
  int c = t >> 7;
  int k = t & 127;
  float lam = clip_lam(decay);
  float w = exp2f((float)(k + 1) * __log2f(lam));
  f32x4 p = ((const f32x4*)havg)[idx];
  f32x4 cin = {0.f, 0.f, 0.f, 0.f};
  if (c > 0) cin = ((const f32x4*)carry)[(size_t)(c - 1) * 128 + d4];
  us4 o;
#pragma unroll
  for (int j = 0; j < 4; ++j) o[j] = f2bf(p[j] + w * cin[j]);
  ((us4*)st)[idx] = o;
}

// ---------------------------------------------------------------------------
// sbar GEMM (bf16 A = st): dbuf + counted vmcnt, 128x128, BK=32, 4 waves.
__global__ __launch_bounds__(256, 4)
void gemm128bf(const unsigned short* __restrict__ A, const unsigned short* __restrict__ Bt,
               const float* __restrict__ extra, float* __restrict__ C) {
  __shared__ __align__(16) char smem[2][16384];   // [buf][A 8KB | B 8KB]

  int nwg = gridDim.x;
  int bid = blockIdx.x;
  int swz = (bid & 7) * (nwg >> 3) + (bid >> 3);
  int tm = swz >> 2, tn = swz & 3;
  int brow = tm << 7, bcol = tn << 7;

  int tid = threadIdx.x;
  int wave = tid >> 6, lane = tid & 63;
  int wr = (wave >> 1) << 6, wc = (wave & 1) << 6;
  const int lr = lane & 15, lkb = lane >> 4;

  const int soct = ((lane & 3) ^ ((lane >> 3) & 3)) << 3;
  const int pm = (lr >> 1) & 3;

  const size_t a_base = (size_t)(brow + (wave << 4) + (lane >> 2)) * 512 + soct;
  const size_t b_base = (size_t)(bcol + (wave << 4) + (lane >> 2)) * 512 + soct;

  f32x4 acc[4][4];
#pragma unroll
  for (int m = 0; m < 4; ++m)
#pragma unroll
    for (int n = 0; n < 4; ++n) acc[m][n] = (f32x4){0.f, 0.f, 0.f, 0.f};

#define STAGE(buf, kt_)                                                        \
  {                                                                            \
    int k0_ = (kt_) << 5;                                                      \
    _Pragma("unroll")                                                          \
    for (int it = 0; it < 2; ++it)                                             \
      gload_lds16(A + a_base + (size_t)(it << 15) + k0_,                       \
                  &smem[buf][(((it << 2) + wave) << 10)]);                     \
    _Pragma("unroll")                                                          \
    for (int it = 0; it < 2; ++it)                                             \
      gload_lds16(Bt + b_base + (size_t)(it << 15) + k0_,                      \
                  &smem[buf][8192 + (((it << 2) + wave) << 10)]);              \
  }

  STAGE(0, 0);

#pragma unroll 2
  for (int kt = 0; kt < 16; ++kt) {
    const int cur = kt & 1;
    if (kt < 15) {
      STAGE(cur ^ 1, kt + 1);
      asm volatile("s_waitcnt vmcnt(4)" ::: "memory");
    } else {
      asm volatile("s_waitcnt vmcnt(0)" ::: "memory");
    }
    __builtin_amdgcn_s_barrier();
    __builtin_amdgcn_sched_barrier(0);

    const unsigned short* As = (const unsigned short*)&smem[cur][0];
    const unsigned short* Bs = (const unsigned short*)&smem[cur][8192];
    short8 af[4], bfr[4];
#pragma unroll
    for (int m = 0; m < 4; ++m)
      af[m] = *(const short8*)(As + (size_t)(wr + (m << 4) + lr) * 32 + ((lkb ^ pm) << 3));
#pragma unroll
    for (int n = 0; n < 4; ++n)
      bfr[n] = *(const short8*)(Bs + (size_t)(wc + (n << 4) + lr) * 32 + ((lkb ^ pm) << 3));

#pragma unroll
    for (int m = 0; m < 4; ++m)
#pragma unroll
      for (int n = 0; n < 4; ++n)
        acc[m][n] = __builtin_amdgcn_mfma_f32_16x16x32_bf16(af[m], bfr[n], acc[m][n], 0, 0, 0);

    __builtin_amdgcn_sched_barrier(0);
    __builtin_amdgcn_s_barrier();
  }
#undef STAGE

  float* tp = (float*)&smem[0][0] + (size_t)wave * 2048;
#pragma unroll
  for (int m = 0; m < 4; ++m) {
#pragma unroll
    for (int n = 0; n < 4; ++n)
#pragma unroll
      for (int j = 0; j < 4; ++j)
        tp[((lkb << 2) + j) * 68 + (n << 4) + lr] = acc[m][n][j];
    __syncthreads();
#pragma unroll
    for (int p = 0; p < 4; ++p) {
      int rl = (p << 2) + (lane >> 4);
      int c0 = (lane & 15) << 2;
      f32x4 v = *(const f32x4*)(tp + rl * 68 + c0);
      int row = brow + wr + (m << 4) + rl;
      int col = bcol + wc + c0;
      f32x4 e = *(const f32x4*)&extra[col];       // bias
      v += e;
      *(f32x4*)&C[(size_t)row * O_DIM + col] = v;
    }
    __syncthreads();
  }
}

// ---------------------------------------------------------------------------
// MAIN GEMM: out[row][o] = x(f32)[row][:] @ Wt_h^T + sbar[row&8191][o].
// A reg-staged: global f32x4 -> v_cvt_pk_bf16_f32 -> swizzled ds_write_b128
// (LDS image identical to gemm128bf's A tile).  B via gload_lds (pre-swizzled
// source).  1-deep pipeline: issue loads(k+1) at top, MFMA(k) covers latency,
// cvt+ds_write after, one __syncthreads per tile.  32KB LDS -> 4 blocks/CU.
__global__ __launch_bounds__(256, 4)
void gemm128xf(const float* __restrict__ X, const unsigned short* __restrict__ Bt,
               const float* __restrict__ extra, float* __restrict__ C) {
  __shared__ __align__(16) char smem[2][16384];   // [buf][A-bf16 8KB | B 8KB]

  int nwg = gridDim.x;
  int bid = blockIdx.x;
  int swz = (bid & 7) * (nwg >> 3) + (bid >> 3);
  int tm = swz >> 2, tn = swz & 3;
  int brow = tm << 7, bcol = tn << 7;

  int tid = threadIdx.x;
  int wave = tid >> 6, lane = tid & 63;
  int wr = (wave >> 1) << 6, wc = (wave & 1) << 6;
  const int lr = lane & 15, lkb = lane >> 4;
  const int pm = (lr >> 1) & 3;

  // A reg-staging: thread t -> row = t>>1 (0..127), half = t&1 (k 0..15/16..31)
  const int arow = tid >> 1, ahalf = tid & 1;
  const float* agp = X + (size_t)(brow + arow) * 512 + (ahalf << 4);
  const int aperm = (arow >> 1) & 3;
  // byte offsets in A half: row*64 + slot*16, slot = (ahalf*2 + j) ^ aperm
  const int aw0 = arow * 64 + (((ahalf << 1) ^ aperm) << 4);
  const int aw1 = aw0 ^ 16;

  // B staging via gload_lds, pre-swizzled global octet
  const int soct = ((lane & 3) ^ ((lane >> 3) & 3)) << 3;
  const size_t b_base = (size_t)(bcol + (wave << 4) + (lane >> 2)) * 512 + soct;

  f32x4 acc[4][4];
#pragma unroll
  for (int m = 0; m < 4; ++m)
#pragma unroll
    for (int n = 0; n < 4; ++n) acc[m][n] = (f32x4){0.f, 0.f, 0.f, 0.f};

  f32x4 a0, a1, a2, a3;                           // in-flight A (16 f32)
#define ALOAD(kt_)                                                             \
  {                                                                            \
    const float* p_ = agp + ((kt_) << 5);                                      \
    a0 = *(const f32x4*)p_;       a1 = *(const f32x4*)(p_ + 4);                \
    a2 = *(const f32x4*)(p_ + 8); a3 = *(const f32x4*)(p_ + 12);               \
  }
#define BSTAGE(buf, kt_)                                                       \
  {                                                                            \
    int k0_ = (kt_) << 5;                                                      \
    _Pragma("unroll")                                                          \
    for (int it = 0; it < 2; ++it)                                             \
      gload_lds16(Bt + b_base + (size_t)(it << 15) + k0_,                      \
                  &smem[buf][8192 + (((it << 2) + wave) << 10)]);              \
  }
#define AWRITE(buf)                                                            \
  {                                                                            \
    u32x4 w0_ = {cvtpk(a0[0], a0[1]), cvtpk(a0[2], a0[3]),                     \
                 cvtpk(a1[0], a1[1]), cvtpk(a1[2], a1[3])};                    \
    u32x4 w1_ = {cvtpk(a2[0], a2[1]), cvtpk(a2[2], a2[3]),                     \
                 cvtpk(a3[0], a3[1]), cvtpk(a3[2], a3[3])};                    \
    *(u32x4*)&smem[buf][aw0] = w0_;                                            \
    *(u32x4*)&smem[buf][aw1] = w1_;                                            \
  }

  // prologue: stage tile 0
  ALOAD(0); BSTAGE(0, 0);
  AWRITE(0);
  __syncthreads();

#pragma unroll 2
  for (int kt = 0; kt < 16; ++kt) {
    const int cur = kt & 1;
    if (kt < 15) { ALOAD(kt + 1); BSTAGE(cur ^ 1, kt + 1); }
    __builtin_amdgcn_sched_barrier(0);            // pin issue-early

    const unsigned short* As = (const unsigned short*)&smem[cur][0];
    const unsigned short* Bs = (const unsigned short*)&smem[cur][8192];
    short8 af[4], bfr[4];
#pragma unroll
    for (int m = 0; m < 4; ++m)
      af[m] = *(const short8*)(As + (size_t)(wr + (m << 4) + lr) * 32 + ((lkb ^ pm) << 3));
#pragma unroll
    for (int n = 0; n < 4; ++n)
      bfr[n] = *(const short8*)(Bs + (size_t)(wc + (n << 4) + lr) * 32 + ((lkb ^ pm) << 3));

#pragma unroll
    for (int m = 0; m < 4; ++m)
#pragma unroll
      for (int n = 0; n < 4; ++n)
        acc[m][n] = __builtin_amdgcn_mfma_f32_16x16x32_bf16(af[m], bfr[n], acc[m][n], 0, 0, 0);

    if (kt < 15) AWRITE(cur ^ 1);                 // compiler waits A-loads here
    __syncthreads();                              // drains vmcnt+lgkm; tile ready
  }
#undef ALOAD
#undef BSTAGE
#undef AWRITE

  // ---- epilogue: per-wave LDS transpose, 16 rows at a time ([16][68] f32) ----
  float* tp = (float*)&smem[0][0] + (size_t)wave * 2048;
#pragma unroll
  for (int m = 0; m < 4; ++m) {
#pragma unroll
    for (int n = 0; n < 4; ++n)
#pragma unroll
      for (int j = 0; j < 4; ++j)
        tp[((lkb << 2) + j) * 68 + (n << 4) + lr] = acc[m][n][j];
    __syncthreads();
#pragma unroll
    for (int p = 0; p < 4; ++p) {
      int rl = (p << 2) + (lane >> 4);
      int c0 = (lane & 15) << 2;
      f32x4 v = *(const f32x4*)(tp + rl * 68 + c0);
      int row = brow + wr + (m << 4) + rl;
      int col = bcol + wc + c0;
      f32x4 e = *(const f32x4*)&extra[(size_t)(row & (T_DIM - 1)) * O_DIM + col];
      v += e;
      *(f32x4*)&C[(size_t)row * O_DIM + col] = v;
    }
    __syncthreads();
  }
}

// ---------------------------------------------------------------------------
extern "C" void kernel_launch(void* const* d_in, const int* in_sizes, int n_in,
                              void* d_out, int out_size, void* d_ws, size_t ws_size,
                              hipStream_t stream) {
  (void)in_sizes; (void)n_in; (void)out_size; (void)ws_size;
  const float* x     = (const float*)d_in[0];   // [8][8192][512]
  const float* W     = (const float*)d_in[1];   // [1024][512]
  const float* bias  = (const float*)d_in[2];   // [512]
  const float* decay = (const float*)d_in[3];   // [1]
  float* out = (float*)d_out;                   // [8][8192][512]

  char* ws = (char*)d_ws;
  size_t off = 0;
  float*          havg  = (float*)(ws + off);          off += 16777216;  // 16 MiB
  unsigned short* st    = (unsigned short*)(ws + off); off += 8388608;   //  8 MiB
  unsigned short* Wt    = (unsigned short*)(ws + off); off += 1048576;   //  1 MiB
  float*          sbar  = (float*)(ws + off);          off += 16777216;  // 16 MiB
  float*          carry = (float*)(ws + off);          off += 131072;    // 128 KiB

  mean_kernel<<<T_DIM * D_DIM / 4 / 256, 256, 0, stream>>>(x, havg);
  wconv_kernel<<<128, 256, 0, stream>>>(W, Wt);
  scanA_kernel<<<NCHUNK * 2, 256, 0, stream>>>(havg, decay);
  scanB_kernel<<<2, 256, 0, stream>>>(havg, decay, carry);
  scanC_kernel<<<T_DIM * D_DIM / 4 / 256, 256, 0, stream>>>(havg, carry, decay, st);
  // sbar[t][o] = states @ W_s + b   (M=8192)
  gemm128bf<<<(T_DIM / 128) * 4, 256, 0, stream>>>(st, Wt + 512 * 512, bias, sbar);
  // out[b*T+t][o] = x @ W_h + sbar[t][o]   (M=65536, f32 A reg-staged)
  gemm128xf<<<(B_DIM * T_DIM / 128) * 4, 256, 0, stream>>>(x, Wt, sbar, out);
}